// Round 4
// baseline (3441.692 us; speedup 1.0000x reference)
//
#include <hip/hip_runtime.h>

typedef _Float16 f16;
typedef _Float16 f16x2 __attribute__((ext_vector_type(2)));
typedef _Float16 f16x4 __attribute__((ext_vector_type(4)));
typedef _Float16 f16x8 __attribute__((ext_vector_type(8)));
typedef float f32x4 __attribute__((ext_vector_type(4)));
typedef unsigned long long u64;

#define L2E 1.4426950408889634f
#define K2E 2.8853900817779268f

// ---- workspace layout (bytes). WS_NEED ~87.4 MB (< 95.8 known-good)
#define O_PQV   0UL            // f32 [16384][512] rows=(t*32+b)  (aliased by GIH2C later)
#define O_GIH2C 0UL            // f16 gate-layout [512][16][4][2][4][16][4]
#define O_CTX   33554432UL     // f16 [16384][256] rows=(t*32+b)   (aliased by DECP later)
#define O_ENCF  41943040UL     // f16 [16384][256] rows=(t*32+b)   (aliased by DECP later)
#define O_DECP  33554432UL     // u64 [512][4096] tagged units (alias CTX+ENCF after gemms)
#define O_GIH1  50331648UL     // f16 gate-layout [512][16][4][2][4][16][4]
#define O_WQV   83886080UL     // f16 [512][256]
#define O_W1    84148224UL     // f16 [1024][512]
#define O_W2    85196800UL     // f16 [1024][512]
#define O_WHH1  86245376UL     // f16 [1024][256]
#define O_WHH2  86769664UL     // f16 [1024][256]
#define O_BQV   87293952UL     // f32 [512]
#define O_B1    87296000UL     // f32 [1024]
#define O_B2    87300096UL     // f32 [1024]
#define O_V2    87304192UL     // f32 [256]  (= -2*V)
#define O_SUMV  87305216UL     // f32 [1]
#define O_CPUB  87305280UL     // u64 [2][4096] tagged c-state units
#define O_H2PUB 87370816UL     // u64 [2][4096] tagged h2-state units
#define WS_NEED 87436352UL

__device__ __forceinline__ float fast_sigmoid(float x){
  float e = __builtin_amdgcn_exp2f(-L2E * x);
  return __builtin_amdgcn_rcpf(1.f + e);
}
__device__ __forceinline__ float fast_tanh(float x){
  float e = __builtin_amdgcn_exp2f(K2E * x);
  return 1.f - 2.f * __builtin_amdgcn_rcpf(1.f + e);
}
__device__ __forceinline__ u64 ld_u64_coh(const u64* p){
  return __hip_atomic_load(p, __ATOMIC_RELAXED, __HIP_MEMORY_SCOPE_AGENT);
}
__device__ __forceinline__ void st_u64_coh(u64* p, u64 v){
  __hip_atomic_store(p, v, __ATOMIC_RELAXED, __HIP_MEMORY_SCOPE_AGENT);
}
__device__ __forceinline__ unsigned int pack2(float a, float b){
  union { unsigned int u; f16 h[2]; } v;
  v.h[0] = (f16)a; v.h[1] = (f16)b;
  return v.u;
}

// ============ prep: weight conversions, biases, tagged cpub[parity1]=bcs =========
__global__ __launch_bounds__(256) void prep_kernel(
    const float* __restrict__ attn_W, const float* __restrict__ attn_b, const float* __restrict__ attn_V,
    const float* __restrict__ l1_Wih, const float* __restrict__ l1_Whh,
    const float* __restrict__ l1_bih, const float* __restrict__ l1_bhh,
    const float* __restrict__ l2_Wih, const float* __restrict__ l2_Whh,
    const float* __restrict__ l2_bih, const float* __restrict__ l2_bhh,
    const float* __restrict__ bcs, char* __restrict__ ws)
{
  long gid = (long)blockIdx.x*256 + threadIdx.x;
  if (gid < 131072){
    int j = (int)(gid >> 8), k = (int)(gid & 255);
    float v = (j < 256) ? attn_W[j*512 + k] : attn_W[(j-256)*512 + 256 + k];
    ((f16*)(ws+O_WQV))[gid] = (f16)(K2E * v);
    return;
  }
  gid -= 131072;
  if (gid < 524288){ ((f16*)(ws+O_W1))[gid] = (f16)l1_Wih[gid]; return; }
  gid -= 524288;
  if (gid < 524288){ ((f16*)(ws+O_W2))[gid] = (f16)l2_Wih[gid]; return; }
  gid -= 524288;
  if (gid < 262144){ ((f16*)(ws+O_WHH1))[gid] = (f16)l1_Whh[gid]; return; }
  gid -= 262144;
  if (gid < 262144){ ((f16*)(ws+O_WHH2))[gid] = (f16)l2_Whh[gid]; return; }
  gid -= 262144;
  if (gid < 512){ ((float*)(ws+O_BQV))[gid] = (gid < 256) ? 0.f : K2E*attn_b[gid-256]; return; }
  gid -= 512;
  if (gid < 1024){ ((float*)(ws+O_B1))[gid] = l1_bih[gid] + l1_bhh[gid]; return; }
  gid -= 1024;
  if (gid < 1024){ ((float*)(ws+O_B2))[gid] = l2_bih[gid] + l2_bhh[gid]; return; }
  gid -= 1024;
  if (gid < 256){ ((float*)(ws+O_V2))[gid] = -2.f*attn_V[gid]; return; }
  gid -= 256;
  if (gid < 4096){
    // tagged initial c-state (tag 0) into cpub parity 1
    int m = (int)(gid >> 7), P = (int)(gid & 127);
    unsigned int d = pack2(bcs[m*256 + 2*P], bcs[m*256 + 2*P + 1]);
    int uidx = ((P>>4)*4 + ((P>>2)&3))*128 + m*4 + (P&3);
    ((u64*)(ws+O_CPUB))[4096 + uidx] = (u64)d;   // high dword (tag) = 0
    return;
  }
  gid -= 4096;
  if (gid == 0){
    float s = 0.f;
    for (int h=0; h<256; h++) s += attn_V[h];
    *((float*)(ws+O_SUMV)) = s;
  }
}

// ============ enc f32 -> f16, rows re-indexed (t*32+b) ============
__global__ __launch_bounds__(256) void encf_kernel(const float* __restrict__ enc, char* __restrict__ ws){
  f16* dst = (f16*)(ws + O_ENCF);
  int gid = blockIdx.x*256 + threadIdx.x;
  int h4 = (gid & 63)*4;
  int t = (gid >> 6) & 511;
  int b = gid >> 15;
  float4 v = *(const float4*)(enc + (size_t)gid*4);
  f16x4 o; o[0] = (f16)v.x; o[1] = (f16)v.y; o[2] = (f16)v.z; o[3] = (f16)v.w;
  *(f16x4*)(dst + (size_t)(t*32+b)*256 + h4) = o;
}

// ============ NT GEMM: rows (t*32+b). MODE 0: f32 C[row][ldc]; MODE 2: f16 gate-layout =========
template<int MODE>
__global__ __launch_bounds__(256) void gemm_nt(const f16* __restrict__ A0, const f16* __restrict__ A1,
     int K0, const f16* __restrict__ B, int ldb, void* __restrict__ Cp, int ldc,
     int K, const float* __restrict__ bias)
{
  __shared__ f16 As[4096];
  __shared__ f16 Bs[4096];
  const int tid = threadIdx.x;
  const int lane = tid & 63;
  const int wave = tid >> 6;
  const int lm = lane & 15, kg = lane >> 4;
  const int mbase = blockIdx.y * 128;
  const int nbase = blockIdx.x * 128;
  const int wm = (wave >> 1) * 64, wn = (wave & 1) * 64;
  f32x4 acc[4][4];
#pragma unroll
  for (int i=0;i<4;i++)
#pragma unroll
    for (int j=0;j<4;j++) acc[i][j] = 0;
  const int r = tid >> 1, seg = tid & 1;
  for (int kc=0; kc<K; kc+=32){
    const f16* Ap = A0; int kk = kc;
    if (A1 && kc >= K0){ Ap = A1; kk = kc - K0; }
    {
      const f16* srcA = Ap + (size_t)(mbase + r)*256 + kk + seg*16;
      f16x8 va0 = *(const f16x8*)(srcA);
      f16x8 va1 = *(const f16x8*)(srcA + 8);
      *(f16x8*)&As[((seg*2+0)*128 + r)*8] = va0;
      *(f16x8*)&As[((seg*2+1)*128 + r)*8] = va1;
      const f16* srcB = B + (size_t)(nbase + r)*ldb + kc + seg*16;
      f16x8 vb0 = *(const f16x8*)(srcB);
      f16x8 vb1 = *(const f16x8*)(srcB + 8);
      *(f16x8*)&Bs[((seg*2+0)*128 + r)*8] = vb0;
      *(f16x8*)&Bs[((seg*2+1)*128 + r)*8] = vb1;
    }
    __syncthreads();
    f16x8 af[4], bfr[4];
#pragma unroll
    for (int i=0;i<4;i++) af[i]  = *(const f16x8*)&As[(kg*128 + wm + i*16 + lm)*8];
#pragma unroll
    for (int j=0;j<4;j++) bfr[j] = *(const f16x8*)&Bs[(kg*128 + wn + j*16 + lm)*8];
#pragma unroll
    for (int i=0;i<4;i++)
#pragma unroll
      for (int j=0;j<4;j++)
        acc[i][j] = __builtin_amdgcn_mfma_f32_16x16x32_f16(af[i], bfr[j], acc[i][j], 0,0,0);
    __syncthreads();
  }
#pragma unroll
  for (int i=0;i<4;i++){
#pragma unroll
    for (int j=0;j<4;j++){
      int col = nbase + wn + j*16 + lm;
      float bv = bias ? bias[col] : 0.f;
      if (MODE == 0){
#pragma unroll
        for (int rr=0;rr<4;rr++){
          int row = mbase + wm + i*16 + kg*4 + rr;
          ((float*)Cp)[(size_t)row*ldc + col] = acc[i][j][rr] + bv;
        }
      } else {
        // gate-layout: row=(t*32+b); addr=(t*16+isl)*2048 + tau*512 + w*256 + kgb*64 + lmg*4 + rr
        int row0 = mbase + wm + i*16 + kg*4;
        int t = row0 >> 5, b = row0 & 31;
        int tau = col >> 8, g = col & 255;
        size_t addr = ((size_t)(t*16 + (g>>4))*4 + tau)*512 + (b>>4)*256 + ((b>>2)&3)*64 + (g&15)*4;
        f16x4 o;
#pragma unroll
        for (int rr=0;rr<4;rr++) o[rr] = (f16)(acc[i][j][rr] + bv);
        *(f16x4*)((f16*)Cp + addr) = o;
      }
    }
  }
}

// ============ fused attention scores + softmax + ctx (pqv rows = t*32+b) ============
__global__ __launch_bounds__(256) void score_ctx_kernel(char* __restrict__ ws,
     const float* __restrict__ enc, const int* __restrict__ inp_len)
{
  __shared__ float s_pq[8][260];
  __shared__ float s_pv[32][260];
  __shared__ float s_sc[8][512];
  __shared__ float s_v2[256];
  __shared__ float s_sv[1];
  const int tid = threadIdx.x;
  const int b = blockIdx.y;
  const int t0 = blockIdx.x * 8;
  const float* pqv = (const float*)(ws + O_PQV);
  f16* ctx = (f16*)(ws + O_CTX);
  const int len = inp_len[b];
  {
    int row = tid >> 5, cb = (tid & 31) * 8;
    const float* src = pqv + (size_t)((t0 + row)*32 + b)*512 + cb;
    *(float4*)&s_pq[row][cb]   = *(const float4*)(src);
    *(float4*)&s_pq[row][cb+4] = *(const float4*)(src+4);
    s_v2[tid] = ((const float*)(ws + O_V2))[tid];
    if (tid == 0) s_sv[0] = *((const float*)(ws + O_SUMV));
  }
  const int tt = tid >> 5;
  const int ss2 = tid & 31;
  for (int st=0; st<16; st++){
    {
      int row = tid >> 3, cb = (tid & 7) * 32;
      const float* src = pqv + (size_t)((st*32 + row)*32 + b)*512 + 256 + cb;
#pragma unroll
      for (int c=0;c<32;c+=4) *(float4*)&s_pv[row][cb+c] = *(const float4*)(src+c);
    }
    __syncthreads();
    float a0=0.f,a1=0.f,a2=0.f,a3=0.f;
#pragma unroll 8
    for (int h=0;h<256;h+=4){
      float4 q = *(const float4*)&s_pq[tt][h];
      float4 p = *(const float4*)&s_pv[ss2][h];
      float4 w = *(const float4*)&s_v2[h];
      float e0 = __builtin_amdgcn_exp2f(q.x+p.x);
      float e1 = __builtin_amdgcn_exp2f(q.y+p.y);
      float e2 = __builtin_amdgcn_exp2f(q.z+p.z);
      float e3 = __builtin_amdgcn_exp2f(q.w+p.w);
      a0 += w.x * __builtin_amdgcn_rcpf(1.f+e0);
      a1 += w.y * __builtin_amdgcn_rcpf(1.f+e1);
      a2 += w.z * __builtin_amdgcn_rcpf(1.f+e2);
      a3 += w.w * __builtin_amdgcn_rcpf(1.f+e3);
    }
    int s = st*32 + ss2;
    float sc = s_sv[0] + ((a0+a1)+(a2+a3));
    if (s >= len) sc = -1.0e9f;
    s_sc[tt][s] = sc;
    __syncthreads();
  }
  {
    float m = -3.0e38f;
#pragma unroll
    for (int k2=0;k2<16;k2++) m = fmaxf(m, s_sc[tt][ss2 + 32*k2]);
#pragma unroll
    for (int off=16; off>=1; off>>=1) m = fmaxf(m, __shfl_xor(m, off, 64));
    float sum = 0.f;
    float ebuf[16];
#pragma unroll
    for (int k2=0;k2<16;k2++){
      float e = __builtin_amdgcn_exp2f((s_sc[tt][ss2+32*k2] - m) * L2E);
      ebuf[k2] = e; sum += e;
    }
#pragma unroll
    for (int off=16; off>=1; off>>=1) sum += __shfl_xor(sum, off, 64);
    float rinv = __builtin_amdgcn_rcpf(sum);
#pragma unroll
    for (int k2=0;k2<16;k2++) s_sc[tt][ss2+32*k2] = ebuf[k2]*rinv;
  }
  __syncthreads();
  float acc[8] = {0,0,0,0,0,0,0,0};
  const int hg = tid & 31;
  for (int st=0; st<16; st++){
    {
      int row = tid >> 3, cb = (tid & 7)*32;
      const float* src = enc + (size_t)(b*512 + st*32 + row)*256 + cb;
#pragma unroll
      for (int c=0;c<32;c+=4) *(float4*)&s_pv[row][cb+c] = *(const float4*)(src+c);
    }
    __syncthreads();
#pragma unroll 4
    for (int si=0; si<32; si++){
      float a = s_sc[tt][st*32+si];
#pragma unroll
      for (int u=0;u<8;u++) acc[u] += a * s_pv[si][hg + 32*u];
    }
    __syncthreads();
  }
#pragma unroll
  for (int u=0;u<8;u++)
    ctx[(size_t)((t0 + tt)*32 + b)*256 + hg + 32*u] = (f16)acc[u];
}

// ============ recurrences: tagged-payload single-hop pipeline ============
// unit u64 = {f16x2 data (low), u32 step-tag (high)}; consumers poll data directly.
// Layer-1: blocks 0-15, 2 waves, all-register gates. Layer-2: blocks 16-31, 4 waves
// (waves 0/1 = x-GEMM + gates, waves 2/3 = h-GEMM, one LDS reduce + one barrier).
__global__ __launch_bounds__(256,1) void rec_kernel(char* __restrict__ ws,
        const float* __restrict__ bhs, const int* __restrict__ inp_len,
        float* __restrict__ out)
{
  const int tid = threadIdx.x;
  const int lane = tid & 63;
  const int wave = tid >> 6;
  const int lm = lane & 15;
  const int kg = lane >> 4;
  u64* cpub  = (u64*)(ws + O_CPUB);
  u64* h2pub = (u64*)(ws + O_H2PUB);
  u64* decp  = (u64*)(ws + O_DECP);

  if (blockIdx.x < 16) {
    if (wave >= 2) return;
    // ---- layer 1 (reference quirk: matmul operand is carry-c; additive path is h_prev)
    const int isl = blockIdx.x;
    const int w = wave;
    const int mg = 16*w + lm;
    const f16* whh1 = (const f16*)(ws + O_WHH1);
    f16x8 bf[4][8];
#pragma unroll
    for (int ta=0;ta<4;ta++)
#pragma unroll
      for (int kc=0;kc<8;kc++)
        bf[ta][kc] = *(const f16x8*)(whh1 + (size_t)(ta*256 + isl*16 + lm)*256 + kc*32 + kg*8);
    float hloc[4];
#pragma unroll
    for (int rr=0;rr<4;rr++) hloc[rr] = bhs[(16*w + kg*4 + rr)*256 + isl*16 + lm];
    // producer unit base (even lanes store pairs for batches 16w+kg*4+rr)
    const int ub0 = (((isl>>1)*4 + (isl&1)*2 + (lm>>3))*32 + 16*w + kg*4)*4 + ((lm>>1)&3);
    const f16* gbase = (const f16*)(ws + O_GIH1) + (size_t)isl*2048 + w*256 + kg*64 + lm*4;
    for (int t=0;t<512;t++){
      f16x4 gv[4];
#pragma unroll
      for (int ta=0;ta<4;ta++) gv[ta] = *(const f16x4*)(gbase + (size_t)t*32768 + ta*512);
      const u64* cp = cpub + (((t+1)&1)<<12);
      const unsigned int tg = (unsigned int)t;
      u64 u[8][4];
      while (true){
#pragma unroll
        for (int kc=0;kc<8;kc++){
          const u64* cb = cp + ((kc*4+kg)*32 + mg)*4;
#pragma unroll
          for (int pq=0;pq<4;pq++) u[kc][pq] = ld_u64_coh(cb + pq);
        }
        bool ok = true;
#pragma unroll
        for (int kc=0;kc<8;kc++)
#pragma unroll
          for (int pq=0;pq<4;pq++) ok &= ((unsigned int)(u[kc][pq] >> 32) == tg);
        if (__all((int)ok)) break;
        __builtin_amdgcn_s_sleep(1);
      }
      f32x4 acc[4];
#pragma unroll
      for (int ta=0;ta<4;ta++) acc[ta] = 0;
#pragma unroll
      for (int kc=0;kc<8;kc++){
        union { f16x8 v; unsigned int d[4]; } af;
#pragma unroll
        for (int pq=0;pq<4;pq++) af.d[pq] = (unsigned int)u[kc][pq];
#pragma unroll
        for (int ta=0;ta<4;ta++)
          acc[ta] = __builtin_amdgcn_mfma_f32_16x16x32_f16(af.v, bf[ta][kc], acc[ta], 0,0,0);
      }
      const u64 tagw = ((u64)(unsigned int)(t+1)) << 32;
      u64 cw[4], hw[4];
#pragma unroll
      for (int rr=0;rr<4;rr++){
        float gi = acc[0][rr] + (float)gv[0][rr];
        float gf = acc[1][rr] + (float)gv[1][rr];
        float gc = acc[2][rr] + (float)gv[2][rr];
        float go = acc[3][rr] + (float)gv[3][rr];
        float cn = fast_sigmoid(gf)*hloc[rr] + fast_sigmoid(gi)*fast_tanh(gc);  // quirk
        float hn = fast_sigmoid(go)*fast_tanh(cn);
        hloc[rr] = hn;
        float cno = __shfl_xor(cn, 1);
        float hno = __shfl_xor(hn, 1);
        cw[rr] = tagw | pack2(cn, cno);
        hw[rr] = tagw | pack2(hn, hno);
      }
      if (!(lm & 1)){
        u64* cd = cpub + ((t&1)<<12) + ub0;
        u64* dd = decp + ((size_t)t<<12) + ub0;
#pragma unroll
        for (int rr=0;rr<4;rr++){ st_u64_coh(cd + rr*4, cw[rr]); st_u64_coh(dd + rr*4, hw[rr]); }
      }
    }
  } else {
    // ---- layer 2 (standard cell, masked freeze)
    const int isl = blockIdx.x - 16;
    const int role = wave >> 1;   // 0 = x-GEMM + gates, 1 = h-GEMM
    const int w = wave & 1;
    const int mg = 16*w + lm;
    __shared__ float s_red[2][64][20];
    if (role == 1){
      const f16* whh2 = (const f16*)(ws + O_WHH2);
      f16x8 bfh[4][8];
#pragma unroll
      for (int ta=0;ta<4;ta++)
#pragma unroll
        for (int kc=0;kc<8;kc++)
          bfh[ta][kc] = *(const f16x8*)(whh2 + (size_t)(ta*256 + isl*16 + lm)*256 + kc*32 + kg*8);
      for (int t=0;t<512;t++){
        const u64* hp = h2pub + (((t+1)&1)<<12);
        const unsigned int tg = (unsigned int)t;
        u64 u[8][4];
        while (true){
#pragma unroll
          for (int kc=0;kc<8;kc++){
            const u64* cb = hp + ((kc*4+kg)*32 + mg)*4;
#pragma unroll
            for (int pq=0;pq<4;pq++) u[kc][pq] = ld_u64_coh(cb + pq);
          }
          bool ok = true;
#pragma unroll
          for (int kc=0;kc<8;kc++)
#pragma unroll
            for (int pq=0;pq<4;pq++) ok &= ((unsigned int)(u[kc][pq] >> 32) == tg);
          if (__all((int)ok)) break;
          __builtin_amdgcn_s_sleep(1);
        }
        f32x4 acc[4];
#pragma unroll
        for (int ta=0;ta<4;ta++) acc[ta] = 0;
#pragma unroll
        for (int kc=0;kc<8;kc++){
          union { f16x8 v; unsigned int d[4]; } af;
#pragma unroll
          for (int pq=0;pq<4;pq++) af.d[pq] = (unsigned int)u[kc][pq];
#pragma unroll
          for (int ta=0;ta<4;ta++)
            acc[ta] = __builtin_amdgcn_mfma_f32_16x16x32_f16(af.v, bfh[ta][kc], acc[ta], 0,0,0);
        }
#pragma unroll
        for (int ta=0;ta<4;ta++) *(f32x4*)&s_red[w][lane][ta*4] = acc[ta];
        __syncthreads();
      }
    } else {
      const f16* w2 = (const f16*)(ws + O_W2);
      f16x8 bfx[4][8];
#pragma unroll
      for (int ta=0;ta<4;ta++)
#pragma unroll
        for (int kc=0;kc<8;kc++)
          bfx[ta][kc] = *(const f16x8*)(w2 + (size_t)(ta*256 + isl*16 + lm)*512 + kc*32 + kg*8);
      float cloc[4] = {0,0,0,0}, hloc[4] = {0,0,0,0};
      int lenv[4];
#pragma unroll
      for (int rr=0;rr<4;rr++) lenv[rr] = inp_len[16*w + kg*4 + rr];
      const int ub0 = (((isl>>1)*4 + (isl&1)*2 + (lm>>3))*32 + 16*w + kg*4)*4 + ((lm>>1)&3);
      const f16* gbase = (const f16*)(ws + O_GIH2C) + (size_t)isl*2048 + w*256 + kg*64 + lm*4;
      for (int t=0;t<512;t++){
        f16x4 gv[4];
#pragma unroll
        for (int ta=0;ta<4;ta++) gv[ta] = *(const f16x4*)(gbase + (size_t)t*32768 + ta*512);
        const u64* xp = decp + ((size_t)t<<12);
        const unsigned int tg = (unsigned int)(t+1);
        u64 u[8][4];
        while (true){
#pragma unroll
          for (int kc=0;kc<8;kc++){
            const u64* cb = xp + ((kc*4+kg)*32 + mg)*4;
#pragma unroll
            for (int pq=0;pq<4;pq++) u[kc][pq] = ld_u64_coh(cb + pq);
          }
          bool ok = true;
#pragma unroll
          for (int kc=0;kc<8;kc++)
#pragma unroll
            for (int pq=0;pq<4;pq++) ok &= ((unsigned int)(u[kc][pq] >> 32) == tg);
          if (__all((int)ok)) break;
          __builtin_amdgcn_s_sleep(1);
        }
        f32x4 acc[4];
#pragma unroll
        for (int ta=0;ta<4;ta++) acc[ta] = 0;
#pragma unroll
        for (int kc=0;kc<8;kc++){
          union { f16x8 v; unsigned int d[4]; } af;
#pragma unroll
          for (int pq=0;pq<4;pq++) af.d[pq] = (unsigned int)u[kc][pq];
#pragma unroll
          for (int ta=0;ta<4;ta++)
            acc[ta] = __builtin_amdgcn_mfma_f32_16x16x32_f16(af.v, bfx[ta][kc], acc[ta], 0,0,0);
        }
        __syncthreads();
#pragma unroll
        for (int ta=0;ta<4;ta++) acc[ta] += *(const f32x4*)&s_red[w][lane][ta*4];
        const u64 tagw = ((u64)(unsigned int)(t+1)) << 32;
        u64 hwv[4];
        float ov[4];
#pragma unroll
        for (int rr=0;rr<4;rr++){
          float gi = acc[0][rr] + (float)gv[0][rr];
          float gf = acc[1][rr] + (float)gv[1][rr];
          float gc = acc[2][rr] + (float)gv[2][rr];
          float go = acc[3][rr] + (float)gv[3][rr];
          float cn = fast_sigmoid(gf)*cloc[rr] + fast_sigmoid(gi)*fast_tanh(gc);
          float hn = fast_sigmoid(go)*fast_tanh(cn);
          bool valid = (t < lenv[rr]);
          cloc[rr] = valid ? cn : cloc[rr];
          float hnew = valid ? hn : hloc[rr];
          hloc[rr] = hnew;
          ov[rr] = valid ? hn : 0.f;
          float hno = __shfl_xor(hnew, 1);
          hwv[rr] = tagw | pack2(hnew, hno);
        }
        if (!(lm & 1)){
          u64* hd = h2pub + ((t&1)<<12) + ub0;
#pragma unroll
          for (int rr=0;rr<4;rr++) st_u64_coh(hd + rr*4, hwv[rr]);
        }
#pragma unroll
        for (int rr=0;rr<4;rr++)
          out[((size_t)(16*w + kg*4 + rr)*512 + t)*256 + isl*16 + lm] = ov[rr];
      }
    }
  }
}

extern "C" void kernel_launch(void* const* d_in, const int* in_sizes, int n_in,
                              void* d_out, int out_size, void* d_ws, size_t ws_size,
                              hipStream_t stream) {
  if (ws_size < WS_NEED) return;  // workspace too small; bail (output stays poison -> visible failure)
  const float* enc    = (const float*)d_in[0];
  const float* bhs    = (const float*)d_in[1];
  const float* bcs    = (const float*)d_in[2];
  const float* attn_W = (const float*)d_in[3];
  const float* attn_b = (const float*)d_in[4];
  const float* attn_V = (const float*)d_in[5];
  const float* l1_Wih = (const float*)d_in[6];
  const float* l1_Whh = (const float*)d_in[7];
  const float* l1_bih = (const float*)d_in[8];
  const float* l1_bhh = (const float*)d_in[9];
  const float* l2_Wih = (const float*)d_in[10];
  const float* l2_Whh = (const float*)d_in[11];
  const float* l2_bih = (const float*)d_in[12];
  const float* l2_bhh = (const float*)d_in[13];
  const int* inp_len  = (const int*)d_in[14];
  char* ws = (char*)d_ws;
  float* out = (float*)d_out;

  // h2pub must start as {0-data, tag 0}; cpub parity-1 is written by prep; poison tags elsewhere never match.
  hipMemsetAsync(ws + O_H2PUB, 0, 65536, stream);
  prep_kernel<<<6700, 256, 0, stream>>>(attn_W, attn_b, attn_V, l1_Wih, l1_Whh, l1_bih, l1_bhh,
                                        l2_Wih, l2_Whh, l2_bih, l2_bhh, bcs, ws);
  encf_kernel<<<4096, 256, 0, stream>>>(enc, ws);
  // pqv = k2*(enc@Wq^T | enc@Wv^T + b), rows (t*32+b)
  gemm_nt<0><<<dim3(4,128), 256, 0, stream>>>((const f16*)(ws+O_ENCF), nullptr, 256,
        (const f16*)(ws+O_WQV), 256, (void*)(ws+O_PQV), 512, 256, (const float*)(ws+O_BQV));
  score_ctx_kernel<<<dim3(64,32), 256, 0, stream>>>(ws, enc, inp_len);
  // gih1 = [enc|ctx]@W1^T + (bih1+bhh1)  (gate-layout)
  gemm_nt<2><<<dim3(8,128), 256, 0, stream>>>((const f16*)(ws+O_ENCF), (const f16*)(ws+O_CTX), 256,
        (const f16*)(ws+O_W1), 512, (void*)(ws+O_GIH1), 0, 512, (const float*)(ws+O_B1));
  // gih2c = ctx@W2R^T + (bih2+bhh2)  (gate-layout; aliases pqv region, dead after score_ctx)
  gemm_nt<2><<<dim3(8,128), 256, 0, stream>>>((const f16*)(ws+O_CTX), nullptr, 256,
        (const f16*)(ws+O_W2)+256, 512, (void*)(ws+O_GIH2C), 0, 256, (const float*)(ws+O_B2));
  // decp aliases CTX+ENCF (dead now); clear stale bits so no tag can accidentally match
  hipMemsetAsync(ws + O_DECP, 0, 16777216, stream);
  rec_kernel<<<32, 256, 0, stream>>>(ws, bhs, inp_len, out);
}